// Round 2
// baseline (304.316 us; speedup 1.0000x reference)
//
#include <hip/hip_runtime.h>

#define NB 4
#define HWN 4096
#define CD 64

typedef short short8 __attribute__((ext_vector_type(8), may_alias));
typedef short short4v __attribute__((ext_vector_type(4), may_alias));
typedef float f32x4 __attribute__((ext_vector_type(4), may_alias));

__device__ constexpr float C1 = 0.18033688011112042f; // log2(e)/8

__device__ __forceinline__ unsigned short f2bf(float f) {
    unsigned u = __builtin_bit_cast(unsigned, f);
    u = (u + 0x7FFFu + ((u >> 16) & 1u)) >> 16;  // RTN-even
    return (unsigned short)u;
}

__device__ __forceinline__ float fexp2(float x) {
#if __has_builtin(__builtin_amdgcn_exp2f)
    return __builtin_amdgcn_exp2f(x);
#else
    return exp2f(x);
#endif
}

// 16x16x16 bf16 MFMA: C/D layout == B layout (row/k = quad*4+r, col/n = lane&15)
__device__ __forceinline__ f32x4 mfma16(short4v a, short4v b, f32x4 c) {
#if __has_builtin(__builtin_amdgcn_mfma_f32_16x16x16bf16_1k)
    return __builtin_amdgcn_mfma_f32_16x16x16bf16_1k(a, b, c, 0, 0, 0);
#else
    f32x4 d;
    asm volatile("v_mfma_f32_16x16x16_bf16 %0, %1, %2, %3\n\ts_nop 7\n\ts_nop 7"
                 : "=v"(d) : "v"(a), "v"(b), "v"(c));
    return d;
#endif
}

// ---------- prep: Q,K fp32 -> bf16 ----------
__global__ __launch_bounds__(256) void cvt_qk(const float* __restrict__ Q,
                                              const float* __restrict__ K,
                                              unsigned short* __restrict__ Qb,
                                              unsigned short* __restrict__ Kb) {
    int i = (blockIdx.x * 256 + threadIdx.x) * 4;
    float4 q = *(const float4*)(Q + i);
    float4 k = *(const float4*)(K + i);
    ushort4 qo, ko;
    qo.x = f2bf(q.x); qo.y = f2bf(q.y); qo.z = f2bf(q.z); qo.w = f2bf(q.w);
    ko.x = f2bf(k.x); ko.y = f2bf(k.y); ko.z = f2bf(k.z); ko.w = f2bf(k.w);
    *(ushort4*)(Qb + i) = qo;
    *(ushort4*)(Kb + i) = ko;
}

// ---------- phase 1: l[n,k] = sum_q exp2(C1 * dot(Q[q],K[k])) ----------
// grid (64, NB, 8): block covers 64 k (16 per wave), z splits q 8 ways (512 q each)
__global__ __launch_bounds__(256, 8) void lsum_kernel(const unsigned short* __restrict__ Qb,
                                                      const unsigned short* __restrict__ Kb,
                                                      float* __restrict__ l) {
    int tid = threadIdx.x;
    int w = tid >> 6, lane = tid & 63, quad = lane >> 4, m16 = lane & 15;
    int n = blockIdx.y;
    int kbase = blockIdx.x * 64 + w * 16;

    const unsigned short* Kp = Kb + ((size_t)(n * HWN + kbase + m16)) * CD + quad * 8;
    short8 kf0 = *(const short8*)(Kp);
    short8 kf1 = *(const short8*)(Kp + 32);

    const unsigned short* Qp = Qb + ((size_t)(n * HWN + blockIdx.z * 512 + m16)) * CD + quad * 8;

    float l0 = 0.f, l1 = 0.f, l2 = 0.f, l3 = 0.f;
    for (int qc = 0; qc < 32; ++qc) {
        short8 qf0 = *(const short8*)(Qp);
        short8 qf1 = *(const short8*)(Qp + 32);
        f32x4 acc = {0.f, 0.f, 0.f, 0.f};
        acc = __builtin_amdgcn_mfma_f32_16x16x32_bf16(kf0, qf0, acc, 0, 0, 0);
        acc = __builtin_amdgcn_mfma_f32_16x16x32_bf16(kf1, qf1, acc, 0, 0, 0);
        l0 += fexp2(acc[0] * C1);
        l1 += fexp2(acc[1] * C1);
        l2 += fexp2(acc[2] * C1);
        l3 += fexp2(acc[3] * C1);
        Qp += 16 * CD;
    }
    for (int d = 1; d < 16; d <<= 1) {
        l0 += __shfl_xor(l0, d);
        l1 += __shfl_xor(l1, d);
        l2 += __shfl_xor(l2, d);
        l3 += __shfl_xor(l3, d);
    }
    if (m16 == 0) {
        float* lp = l + n * HWN + kbase + quad * 4;
        atomicAdd(lp + 0, l0);
        atomicAdd(lp + 1, l1);
        atomicAdd(lp + 2, l2);
        atomicAdd(lp + 3, l3);
    }
}

// ---------- prep: Vt[n][c][k] = bf16(V[n][k][c] / l[n][k]) ----------
__global__ __launch_bounds__(256) void prep_v(const float* __restrict__ V,
                                              const float* __restrict__ l,
                                              unsigned short* __restrict__ Vt) {
    __shared__ float rl[64];
    __shared__ float tile[64][65];
    int tid = threadIdx.x, n = blockIdx.y, kbase = blockIdx.x * 64;
    if (tid < 64) rl[tid] = 1.0f / l[n * HWN + kbase + tid];
    __syncthreads();
#pragma unroll
    for (int i = 0; i < 16; ++i) {
        int e = i * 256 + tid;
        int k = e >> 6, c = e & 63;
        tile[c][k] = V[((size_t)(n * HWN + kbase + k)) * CD + c] * rl[k];
    }
    __syncthreads();
#pragma unroll
    for (int i = 0; i < 16; ++i) {
        int e = i * 256 + tid;
        int c = e >> 6, kk = e & 63;
        Vt[((size_t)(n * CD + c)) * HWN + kbase + kk] = f2bf(tile[c][kk]);
    }
}

// ---------- phase 2: outT[c][q] += Vt[c][k] * exp2(C1*S'[k][q]) ----------
// grid (256 q-tiles, NB, 2): 4 waves split k within block (LDS reduce), z=2 partial slices
__global__ __launch_bounds__(256, 8) void attn_kernel(const unsigned short* __restrict__ Qb,
                                                      const unsigned short* __restrict__ Kb,
                                                      const unsigned short* __restrict__ Vt,
                                                      float* __restrict__ partial) {
    __shared__ float redu[4][16][68];  // [wave][q][c], stride 68 for b128 alignment
    int tid = threadIdx.x;
    int w = tid >> 6, lane = tid & 63, quad = lane >> 4, m16 = lane & 15;
    int n = blockIdx.y;
    int qbase = blockIdx.x * 16;
    int zb = blockIdx.z;
    int kslice = (zb * 4 + w) * 512;

    const unsigned short* Qp = Qb + ((size_t)(n * HWN + qbase + m16)) * CD + quad * 8;
    short8 qf0 = *(const short8*)(Qp);
    short8 qf1 = *(const short8*)(Qp + 32);

    const unsigned short* Kp = Kb + ((size_t)(n * HWN + kslice + m16)) * CD + quad * 8;
    const unsigned short* Vp = Vt + ((size_t)(n * CD + m16)) * HWN + kslice + quad * 4;

    f32x4 o0 = {0.f, 0.f, 0.f, 0.f}, o1 = o0, o2 = o0, o3 = o0;

    for (int it = 0; it < 32; ++it) {
        short8 kf0 = *(const short8*)(Kp);
        short8 kf1 = *(const short8*)(Kp + 32);
        // S'[k=quad*4+r][q=m16], k-tile of 16 (A=K rows, B=Q cols), full c=64
        f32x4 s = {0.f, 0.f, 0.f, 0.f};
        s = __builtin_amdgcn_mfma_f32_16x16x32_bf16(kf0, qf0, s, 0, 0, 0);
        s = __builtin_amdgcn_mfma_f32_16x16x32_bf16(kf1, qf1, s, 0, 0, 0);
        // P' in C-layout == B-frag of mfma16 directly; no LDS round trip
        short4v pf;
        pf[0] = (short)f2bf(fexp2(s[0] * C1));
        pf[1] = (short)f2bf(fexp2(s[1] * C1));
        pf[2] = (short)f2bf(fexp2(s[2] * C1));
        pf[3] = (short)f2bf(fexp2(s[3] * C1));
        short4v v0 = *(const short4v*)(Vp);
        short4v v1 = *(const short4v*)(Vp + 16 * HWN);
        short4v v2 = *(const short4v*)(Vp + 32 * HWN);
        short4v v3 = *(const short4v*)(Vp + 48 * HWN);
        o0 = mfma16(v0, pf, o0);
        o1 = mfma16(v1, pf, o1);
        o2 = mfma16(v2, pf, o2);
        o3 = mfma16(v3, pf, o3);
        Kp += 16 * CD;
        Vp += 16;
    }
    // o{t}[r] = outT[c = t*16 + quad*4 + r][q = qbase + m16]
    float* rp = &redu[w][m16][quad * 4];
    *(f32x4*)(rp)      = o0;
    *(f32x4*)(rp + 16) = o1;
    *(f32x4*)(rp + 32) = o2;
    *(f32x4*)(rp + 48) = o3;
    __syncthreads();
    // combine 4 waves: thread -> one float4 of the 16x64 tile
    int q = tid >> 4, c4 = (tid & 15) * 4;
    f32x4 a = *(const f32x4*)&redu[0][q][c4];
    f32x4 b = *(const f32x4*)&redu[1][q][c4];
    f32x4 c = *(const f32x4*)&redu[2][q][c4];
    f32x4 d = *(const f32x4*)&redu[3][q][c4];
    a = (a + b) + (c + d);
    *(f32x4*)(partial + (size_t)zb * (NB * HWN * CD) +
              ((size_t)(n * HWN + qbase + q)) * CD + c4) = a;
}

// ---------- final: out = partial[0] + partial[1] ----------
__global__ __launch_bounds__(256) void reduce_out(const float* __restrict__ p,
                                                  float* __restrict__ out) {
    int i = (blockIdx.x * 256 + threadIdx.x) * 4;
    f32x4 a = *(const f32x4*)(p + i);
    f32x4 b = *(const f32x4*)(p + (NB * HWN * CD) + i);
    a = a + b;
    *(f32x4*)(out + i) = a;
}

extern "C" void kernel_launch(void* const* d_in, const int* in_sizes, int n_in,
                              void* d_out, int out_size, void* d_ws, size_t ws_size,
                              hipStream_t stream) {
    const float* Q = (const float*)d_in[0];
    const float* K = (const float*)d_in[1];
    const float* V = (const float*)d_in[2];
    float* out = (float*)d_out;

    char* ws = (char*)d_ws;
    unsigned short* Qb = (unsigned short*)(ws);                    // 2 MB
    unsigned short* Kb = (unsigned short*)(ws + (1u << 21));       // 2 MB
    unsigned short* Vt = (unsigned short*)(ws + (2u << 21));       // 2 MB
    float* l       = (float*)(ws + (3u << 21));                    // 64 KB
    float* partial = (float*)(ws + (4u << 21));                    // 8 MB (2 slices)

    hipMemsetAsync(l, 0, (size_t)NB * HWN * sizeof(float), stream);

    cvt_qk<<<1024, 256, 0, stream>>>(Q, K, Qb, Kb);
    lsum_kernel<<<dim3(64, NB, 8), 256, 0, stream>>>(Qb, Kb, l);
    prep_v<<<dim3(64, NB), 256, 0, stream>>>(V, l, Vt);
    attn_kernel<<<dim3(256, NB, 2), 256, 0, stream>>>(Qb, Kb, Vt, partial);
    reduce_out<<<1024, 256, 0, stream>>>(partial, out);
}

// Round 3
// 260.246 us; speedup vs baseline: 1.1693x; 1.1693x over previous
//
#include <hip/hip_runtime.h>

#define NB 4
#define HWN 4096
#define CD 64

typedef short short8 __attribute__((ext_vector_type(8), may_alias));
typedef float f32x4 __attribute__((ext_vector_type(4), may_alias));

__device__ constexpr float C1 = 0.18033688011112042f; // log2(e)/8

__device__ __forceinline__ unsigned short f2bf(float f) {
    unsigned u = __builtin_bit_cast(unsigned, f);
    u = (u + 0x7FFFu + ((u >> 16) & 1u)) >> 16;  // RTN-even
    return (unsigned short)u;
}

__device__ __forceinline__ float fexp2(float x) {
#if __has_builtin(__builtin_amdgcn_exp2f)
    return __builtin_amdgcn_exp2f(x);
#else
    return exp2f(x);
#endif
}

// ---------- prep: Q,K fp32 -> bf16 ----------
__global__ __launch_bounds__(256) void cvt_qk(const float* __restrict__ Q,
                                              const float* __restrict__ K,
                                              unsigned short* __restrict__ Qb,
                                              unsigned short* __restrict__ Kb) {
    int i = (blockIdx.x * 256 + threadIdx.x) * 4;
    float4 q = *(const float4*)(Q + i);
    float4 k = *(const float4*)(K + i);
    ushort4 qo, ko;
    qo.x = f2bf(q.x); qo.y = f2bf(q.y); qo.z = f2bf(q.z); qo.w = f2bf(q.w);
    ko.x = f2bf(k.x); ko.y = f2bf(k.y); ko.z = f2bf(k.z); ko.w = f2bf(k.w);
    *(ushort4*)(Qb + i) = qo;
    *(ushort4*)(Kb + i) = ko;
}

// ---------- phase 1: l[n,k] = sum_q exp2(C1 * dot(Q[q],K[k])) ----------
// A=K (m=key), B=Q (n=query). C/D: row(=k)=quad*4+r, col(=q)=lane&15
__global__ __launch_bounds__(256, 8) void lsum_kernel(const unsigned short* __restrict__ Qb,
                                                      const unsigned short* __restrict__ Kb,
                                                      float* __restrict__ l) {
    int tid = threadIdx.x;
    int w = tid >> 6, lane = tid & 63, quad = lane >> 4, m16 = lane & 15;
    int n = blockIdx.y;
    int kbase = blockIdx.x * 64 + w * 16;

    const unsigned short* Kp = Kb + ((size_t)(n * HWN + kbase + m16)) * CD + quad * 8;
    short8 kf0 = *(const short8*)(Kp);
    short8 kf1 = *(const short8*)(Kp + 32);

    const unsigned short* Qp = Qb + ((size_t)(n * HWN + blockIdx.z * 512 + m16)) * CD + quad * 8;

    float l0 = 0.f, l1 = 0.f, l2 = 0.f, l3 = 0.f;
    for (int qc = 0; qc < 32; ++qc) {
        short8 qf0 = *(const short8*)(Qp);
        short8 qf1 = *(const short8*)(Qp + 32);
        f32x4 acc = {0.f, 0.f, 0.f, 0.f};
        acc = __builtin_amdgcn_mfma_f32_16x16x32_bf16(kf0, qf0, acc, 0, 0, 0);
        acc = __builtin_amdgcn_mfma_f32_16x16x32_bf16(kf1, qf1, acc, 0, 0, 0);
        l0 += fexp2(acc[0] * C1);
        l1 += fexp2(acc[1] * C1);
        l2 += fexp2(acc[2] * C1);
        l3 += fexp2(acc[3] * C1);
        Qp += 16 * CD;
    }
    for (int d = 1; d < 16; d <<= 1) {
        l0 += __shfl_xor(l0, d);
        l1 += __shfl_xor(l1, d);
        l2 += __shfl_xor(l2, d);
        l3 += __shfl_xor(l3, d);
    }
    if (m16 == 0) {
        float* lp = l + n * HWN + kbase + quad * 4;
        atomicAdd(lp + 0, l0);
        atomicAdd(lp + 1, l1);
        atomicAdd(lp + 2, l2);
        atomicAdd(lp + 3, l3);
    }
}

// ---------- prep: Vt[n][c][k] = bf16(V[n][k][c] / l[n][k]) ----------
__global__ __launch_bounds__(256) void prep_v(const float* __restrict__ V,
                                              const float* __restrict__ l,
                                              unsigned short* __restrict__ Vt) {
    __shared__ float rl[64];
    __shared__ float tile[64][65];
    int tid = threadIdx.x, n = blockIdx.y, kbase = blockIdx.x * 64;
    if (tid < 64) rl[tid] = 1.0f / l[n * HWN + kbase + tid];
    __syncthreads();
#pragma unroll
    for (int i = 0; i < 16; ++i) {
        int e = i * 256 + tid;
        int k = e >> 6, c = e & 63;
        tile[c][k] = V[((size_t)(n * HWN + kbase + k)) * CD + c] * rl[k];
    }
    __syncthreads();
#pragma unroll
    for (int i = 0; i < 16; ++i) {
        int e = i * 256 + tid;
        int c = e >> 6, kk = e & 63;
        Vt[((size_t)(n * CD + c)) * HWN + kbase + kk] = f2bf(tile[c][kk]);
    }
}

// ---------- phase 2: out[q,c] += sum_k exp2(C1*s_qk) * Vt[c][k] ----------
// grid (256 q-tiles, NB, 2). Block: 4 waves, each a different 512-k slice of
// the same 16 q rows; LDS-reduce across waves; 2-way fp32 atomicAdd to out.
__global__ __launch_bounds__(256, 8) void attn_kernel(const unsigned short* __restrict__ Qb,
                                                      const unsigned short* __restrict__ Kb,
                                                      const unsigned short* __restrict__ Vt,
                                                      float* __restrict__ out) {
    // 17408 B shared: during the k-loop, per-wave P buffers (16x40 bf16 each,
    // byte offset w*1280); after a barrier, reused as redu[4][16][68] floats.
    __shared__ float redu[4][16][68];
    int tid = threadIdx.x;
    int w = tid >> 6, lane = tid & 63, quad = lane >> 4, m16 = lane & 15;
    int n = blockIdx.y;
    int qbase = blockIdx.x * 16;
    int kslice = (blockIdx.z * 4 + w) * 512;

    const unsigned short* Qp = Qb + ((size_t)(n * HWN + qbase + m16)) * CD + quad * 8;
    short8 qf0 = *(const short8*)(Qp);
    short8 qf1 = *(const short8*)(Qp + 32);

    const unsigned short* Kp = Kb + ((size_t)(n * HWN + kslice + m16)) * CD + quad * 8;
    const unsigned short* Vp = Vt + ((size_t)(n * CD + m16)) * HWN + kslice + quad * 8;

    f32x4 o[4];
#pragma unroll
    for (int ct = 0; ct < 4; ++ct) o[ct] = f32x4{0.f, 0.f, 0.f, 0.f};

    short* pw = (short*)&redu[0][0][0] + w * 640;  // 16 rows x 40 bf16, per-wave

    for (int it = 0; it < 16; ++it) {
        // S tile: 16q x 32k (A=Q m=q, B=K n=k). C/D: row(q)=quad*4+r, col(k)=m16
        short8 kf00 = *(const short8*)(Kp);
        short8 kf01 = *(const short8*)(Kp + 32);
        short8 kf10 = *(const short8*)(Kp + 16 * CD);
        short8 kf11 = *(const short8*)(Kp + 16 * CD + 32);
        f32x4 s0 = {0.f, 0.f, 0.f, 0.f}, s1 = {0.f, 0.f, 0.f, 0.f};
        s0 = __builtin_amdgcn_mfma_f32_16x16x32_bf16(qf0, kf00, s0, 0, 0, 0);
        s0 = __builtin_amdgcn_mfma_f32_16x16x32_bf16(qf1, kf01, s0, 0, 0, 0);
        s1 = __builtin_amdgcn_mfma_f32_16x16x32_bf16(qf0, kf10, s1, 0, 0, 0);
        s1 = __builtin_amdgcn_mfma_f32_16x16x32_bf16(qf1, kf11, s1, 0, 0, 0);

        // P = exp2(C1*s) -> LDS rows=q, cols=k (stride 40); in-wave DS is in-order
        short* prow = pw + (quad * 4) * 40 + m16;
#pragma unroll
        for (int r = 0; r < 4; ++r) {
            prow[r * 40]      = (short)f2bf(fexp2(s0[r] * C1));
            prow[r * 40 + 16] = (short)f2bf(fexp2(s1[r] * C1));
        }
        // A-frag read: A[m=q=m16][k=quad*8+j]
        short8 pf = *(const short8*)(pw + m16 * 40 + quad * 8);

#pragma unroll
        for (int ct = 0; ct < 4; ++ct) {
            short8 vf = *(const short8*)(Vp + (size_t)ct * 16 * HWN);
            o[ct] = __builtin_amdgcn_mfma_f32_16x16x32_bf16(pf, vf, o[ct], 0, 0, 0);
        }
        Kp += 32 * CD;
        Vp += 32;
    }

    // o[ct][r] = O_partial[q = quad*4+r][c = ct*16 + m16] for this wave's k-slice
    __syncthreads();  // all waves done reading their P buffers before redu overwrite
#pragma unroll
    for (int ct = 0; ct < 4; ++ct)
#pragma unroll
        for (int r = 0; r < 4; ++r)
            redu[w][quad * 4 + r][ct * 16 + m16] = o[ct][r];
    __syncthreads();

    int q = tid >> 4, c4 = (tid & 15) * 4;
    f32x4 a = *(const f32x4*)&redu[0][q][c4];
    f32x4 b = *(const f32x4*)&redu[1][q][c4];
    f32x4 c = *(const f32x4*)&redu[2][q][c4];
    f32x4 d = *(const f32x4*)&redu[3][q][c4];
    a = (a + b) + (c + d);
    float* op = out + ((size_t)(n * HWN + qbase + q)) * CD + c4;
    atomicAdd(op + 0, a[0]);
    atomicAdd(op + 1, a[1]);
    atomicAdd(op + 2, a[2]);
    atomicAdd(op + 3, a[3]);
}

extern "C" void kernel_launch(void* const* d_in, const int* in_sizes, int n_in,
                              void* d_out, int out_size, void* d_ws, size_t ws_size,
                              hipStream_t stream) {
    const float* Q = (const float*)d_in[0];
    const float* K = (const float*)d_in[1];
    const float* V = (const float*)d_in[2];
    float* out = (float*)d_out;

    char* ws = (char*)d_ws;
    unsigned short* Qb = (unsigned short*)(ws);                    // 2 MB
    unsigned short* Kb = (unsigned short*)(ws + (1u << 21));       // 2 MB
    unsigned short* Vt = (unsigned short*)(ws + (2u << 21));       // 2 MB
    float* l          = (float*)(ws + (3u << 21));                 // 64 KB

    hipMemsetAsync(out, 0, (size_t)NB * HWN * CD * sizeof(float), stream);
    hipMemsetAsync(l, 0, (size_t)NB * HWN * sizeof(float), stream);

    cvt_qk<<<1024, 256, 0, stream>>>(Q, K, Qb, Kb);
    lsum_kernel<<<dim3(64, NB, 8), 256, 0, stream>>>(Qb, Kb, l);
    prep_v<<<dim3(64, NB), 256, 0, stream>>>(V, l, Vt);
    attn_kernel<<<dim3(256, NB, 2), 256, 0, stream>>>(Qb, Kb, Vt, out);
}

// Round 4
// 224.111 us; speedup vs baseline: 1.3579x; 1.1612x over previous
//
#include <hip/hip_runtime.h>

#define NB 4
#define HWN 4096
#define CD 64

typedef short short8 __attribute__((ext_vector_type(8), may_alias));
typedef float f32x4 __attribute__((ext_vector_type(4), may_alias));

__device__ constexpr float C1 = 0.18033688011112042f; // log2(e)/8

__device__ __forceinline__ unsigned short f2bf(float f) {
    unsigned u = __builtin_bit_cast(unsigned, f);
    u = (u + 0x7FFFu + ((u >> 16) & 1u)) >> 16;  // RTN-even
    return (unsigned short)u;
}

__device__ __forceinline__ float fexp2(float x) {
#if __has_builtin(__builtin_amdgcn_exp2f)
    return __builtin_amdgcn_exp2f(x);
#else
    return exp2f(x);
#endif
}

// ---------- prep: Q,K fp32 -> bf16 ----------
__global__ __launch_bounds__(256) void cvt_qk(const float* __restrict__ Q,
                                              const float* __restrict__ K,
                                              unsigned short* __restrict__ Qb,
                                              unsigned short* __restrict__ Kb) {
    int i = (blockIdx.x * 256 + threadIdx.x) * 4;
    float4 q = *(const float4*)(Q + i);
    float4 k = *(const float4*)(K + i);
    ushort4 qo, ko;
    qo.x = f2bf(q.x); qo.y = f2bf(q.y); qo.z = f2bf(q.z); qo.w = f2bf(q.w);
    ko.x = f2bf(k.x); ko.y = f2bf(k.y); ko.z = f2bf(k.z); ko.w = f2bf(k.w);
    *(ushort4*)(Qb + i) = qo;
    *(ushort4*)(Kb + i) = ko;
}

// ---------- phase 1: l[n,k] = sum_q exp2(C1 * dot(Q[q],K[k])) ----------
// Wave holds 32 stationary k (two 16-k A-frag sets); all 4 waves of a block
// stream the SAME Q-slice (identical addresses -> L1/MSHR dedup).
// grid (32 k-tiles of 128, NB, 8 q-slices of 512)
__global__ __launch_bounds__(256, 8) void lsum_kernel(const unsigned short* __restrict__ Qb,
                                                      const unsigned short* __restrict__ Kb,
                                                      float* __restrict__ l) {
    int tid = threadIdx.x;
    int w = tid >> 6, lane = tid & 63, quad = lane >> 4, m16 = lane & 15;
    int n = blockIdx.y;
    int kbase = blockIdx.x * 128 + w * 32;

    const unsigned short* Kp = Kb + ((size_t)(n * HWN + kbase + m16)) * CD + quad * 8;
    short8 ka0 = *(const short8*)(Kp);
    short8 ka1 = *(const short8*)(Kp + 32);
    short8 kb0 = *(const short8*)(Kp + 16 * CD);
    short8 kb1 = *(const short8*)(Kp + 16 * CD + 32);

    const unsigned short* Qp = Qb + ((size_t)(n * HWN + blockIdx.z * 512 + m16)) * CD + quad * 8;

    float lA[4] = {0.f, 0.f, 0.f, 0.f};
    float lB[4] = {0.f, 0.f, 0.f, 0.f};
    for (int qc = 0; qc < 32; ++qc) {
        short8 qf0 = *(const short8*)(Qp);
        short8 qf1 = *(const short8*)(Qp + 32);
        f32x4 a = {0.f, 0.f, 0.f, 0.f}, b = {0.f, 0.f, 0.f, 0.f};
        a = __builtin_amdgcn_mfma_f32_16x16x32_bf16(ka0, qf0, a, 0, 0, 0);
        a = __builtin_amdgcn_mfma_f32_16x16x32_bf16(ka1, qf1, a, 0, 0, 0);
        b = __builtin_amdgcn_mfma_f32_16x16x32_bf16(kb0, qf0, b, 0, 0, 0);
        b = __builtin_amdgcn_mfma_f32_16x16x32_bf16(kb1, qf1, b, 0, 0, 0);
#pragma unroll
        for (int r = 0; r < 4; ++r) {
            lA[r] += fexp2(a[r] * C1);
            lB[r] += fexp2(b[r] * C1);
        }
        Qp += 16 * CD;
    }
#pragma unroll
    for (int r = 0; r < 4; ++r)
        for (int d = 1; d < 16; d <<= 1) {
            lA[r] += __shfl_xor(lA[r], d);
            lB[r] += __shfl_xor(lB[r], d);
        }
    if (m16 == 0) {
        float* lp = l + n * HWN + kbase + quad * 4;
#pragma unroll
        for (int r = 0; r < 4; ++r) {
            atomicAdd(lp + r, lA[r]);
            atomicAdd(lp + 16 + r, lB[r]);
        }
    }
}

// ---------- prep: Vt[n][c][k] = bf16(V[n][k][c] / l[n][k]) ----------
__global__ __launch_bounds__(256) void prep_v(const float* __restrict__ V,
                                              const float* __restrict__ l,
                                              unsigned short* __restrict__ Vt) {
    __shared__ float rl[64];
    __shared__ float tile[64][65];
    int tid = threadIdx.x, n = blockIdx.y, kbase = blockIdx.x * 64;
    if (tid < 64) rl[tid] = 1.0f / l[n * HWN + kbase + tid];
    __syncthreads();
#pragma unroll
    for (int i = 0; i < 16; ++i) {
        int e = i * 256 + tid;
        int k = e >> 6, c = e & 63;
        tile[c][k] = V[((size_t)(n * HWN + kbase + k)) * CD + c] * rl[k];
    }
    __syncthreads();
#pragma unroll
    for (int i = 0; i < 16; ++i) {
        int e = i * 256 + tid;
        int c = e >> 6, kk = e & 63;
        Vt[((size_t)(n * CD + c)) * HWN + kbase + kk] = f2bf(tile[c][kk]);
    }
}

// ---------- phase 2: out[q,c] = sum_k exp2(C1*s_qk) * Vt[c][k] ----------
// grid (64 q-blocks of 64, NB, 2 k-slices). All 4 waves of a block share the
// SAME 2048-k slice (identical K/V addresses -> L1 dedup); wave w owns q-tile
// qbase + w*16. Plain stores to per-slice partial buffers; no atomics.
__global__ __launch_bounds__(256, 8) void attn_kernel(const unsigned short* __restrict__ Qb,
                                                      const unsigned short* __restrict__ Kb,
                                                      const unsigned short* __restrict__ Vt,
                                                      float* __restrict__ partial) {
    __shared__ short plds[4][16][40];  // per-wave P buffer, stride 40 bf16
    int tid = threadIdx.x;
    int w = tid >> 6, lane = tid & 63, quad = lane >> 4, m16 = lane & 15;
    int n = blockIdx.y;
    int qbase = blockIdx.x * 64 + w * 16;
    int kslice = blockIdx.z * 2048;

    const unsigned short* Qp = Qb + ((size_t)(n * HWN + qbase + m16)) * CD + quad * 8;
    short8 qf0 = *(const short8*)(Qp);
    short8 qf1 = *(const short8*)(Qp + 32);

    const unsigned short* Kp = Kb + ((size_t)(n * HWN + kslice + m16)) * CD + quad * 8;
    const unsigned short* Vp = Vt + ((size_t)(n * CD + m16)) * HWN + kslice + quad * 8;

    f32x4 o[4];
#pragma unroll
    for (int ct = 0; ct < 4; ++ct) o[ct] = f32x4{0.f, 0.f, 0.f, 0.f};

    short* pw = &plds[w][0][0];

    for (int it = 0; it < 64; ++it) {
        // S tile: 16q x 32k (A=Q m=q, B=K n=k). C/D: row(q)=quad*4+r, col(k)=m16
        short8 kf00 = *(const short8*)(Kp);
        short8 kf01 = *(const short8*)(Kp + 32);
        short8 kf10 = *(const short8*)(Kp + 16 * CD);
        short8 kf11 = *(const short8*)(Kp + 16 * CD + 32);
        f32x4 s0 = {0.f, 0.f, 0.f, 0.f}, s1 = {0.f, 0.f, 0.f, 0.f};
        s0 = __builtin_amdgcn_mfma_f32_16x16x32_bf16(qf0, kf00, s0, 0, 0, 0);
        s0 = __builtin_amdgcn_mfma_f32_16x16x32_bf16(qf1, kf01, s0, 0, 0, 0);
        s1 = __builtin_amdgcn_mfma_f32_16x16x32_bf16(qf0, kf10, s1, 0, 0, 0);
        s1 = __builtin_amdgcn_mfma_f32_16x16x32_bf16(qf1, kf11, s1, 0, 0, 0);

        // P = exp2(C1*s) -> per-wave LDS (rows=q, stride 40); in-wave DS in-order
        short* prow = pw + (quad * 4) * 40 + m16;
#pragma unroll
        for (int r = 0; r < 4; ++r) {
            prow[r * 40]      = (short)f2bf(fexp2(s0[r] * C1));
            prow[r * 40 + 16] = (short)f2bf(fexp2(s1[r] * C1));
        }
        // A-frag read: A[m=q=m16][k=quad*8+j]
        short8 pf = *(const short8*)(pw + m16 * 40 + quad * 8);

#pragma unroll
        for (int ct = 0; ct < 4; ++ct) {
            short8 vf = *(const short8*)(Vp + (size_t)ct * 16 * HWN);
            o[ct] = __builtin_amdgcn_mfma_f32_16x16x32_bf16(pf, vf, o[ct], 0, 0, 0);
        }
        Kp += 32 * CD;
        Vp += 32;
        if ((it & 7) == 7) __syncthreads();  // keep 4 waves in lockstep for L1 reuse
    }

    // o[ct][r] = O_partial[q = quad*4+r][c = ct*16 + m16]; plain stores
    float* pp = partial + (size_t)blockIdx.z * (NB * HWN * CD) +
                ((size_t)(n * HWN + qbase + quad * 4)) * CD + m16;
#pragma unroll
    for (int ct = 0; ct < 4; ++ct)
#pragma unroll
        for (int r = 0; r < 4; ++r)
            pp[r * CD + ct * 16] = o[ct][r];
}

// ---------- final: out = partial[0] + partial[1] ----------
__global__ __launch_bounds__(256) void reduce_out(const float* __restrict__ p,
                                                  float* __restrict__ out) {
    int i = (blockIdx.x * 256 + threadIdx.x) * 4;
    f32x4 a = *(const f32x4*)(p + i);
    f32x4 b = *(const f32x4*)(p + (NB * HWN * CD) + i);
    a = a + b;
    *(f32x4*)(out + i) = a;
}

extern "C" void kernel_launch(void* const* d_in, const int* in_sizes, int n_in,
                              void* d_out, int out_size, void* d_ws, size_t ws_size,
                              hipStream_t stream) {
    const float* Q = (const float*)d_in[0];
    const float* K = (const float*)d_in[1];
    const float* V = (const float*)d_in[2];
    float* out = (float*)d_out;

    char* ws = (char*)d_ws;
    unsigned short* Qb = (unsigned short*)(ws);                    // 2 MB
    unsigned short* Kb = (unsigned short*)(ws + (1u << 21));       // 2 MB
    unsigned short* Vt = (unsigned short*)(ws + (2u << 21));       // 2 MB
    float* l       = (float*)(ws + (3u << 21));                    // 64 KB
    float* partial = (float*)(ws + (4u << 21));                    // 8 MB (2 slices)

    hipMemsetAsync(l, 0, (size_t)NB * HWN * sizeof(float), stream);

    cvt_qk<<<1024, 256, 0, stream>>>(Q, K, Qb, Kb);
    lsum_kernel<<<dim3(32, NB, 8), 256, 0, stream>>>(Qb, Kb, l);
    prep_v<<<dim3(64, NB), 256, 0, stream>>>(V, l, Vt);
    attn_kernel<<<dim3(64, NB, 2), 256, 0, stream>>>(Qb, Kb, Vt, partial);
    reduce_out<<<1024, 256, 0, stream>>>(partial, out);
}

// Round 5
// 139.901 us; speedup vs baseline: 2.1752x; 1.6019x over previous
//
#include <hip/hip_runtime.h>

#define NB 4
#define HWN 4096
#define CD 64
#define NSTRIDE (HWN * CD)  // 262144 elems per batch in all swizzled buffers

typedef short short8 __attribute__((ext_vector_type(8), may_alias));
typedef float f32x4 __attribute__((ext_vector_type(4), may_alias));

__device__ constexpr float C1 = 0.18033688011112042f; // log2(e)/8

__device__ __forceinline__ unsigned short f2bf(float f) {
    unsigned u = __builtin_bit_cast(unsigned, f);
    u = (u + 0x7FFFu + ((u >> 16) & 1u)) >> 16;  // RTN-even
    return (unsigned short)u;
}

__device__ __forceinline__ float fexp2(float x) {
#if __has_builtin(__builtin_amdgcn_exp2f)
    return __builtin_amdgcn_exp2f(x);
#else
    return exp2f(x);
#endif
}

// Frag-major swizzle for a row-major [R][64] matrix, 16-row tiles:
// elem(row, c) -> tile = row>>4, half = c>>5, lane l = ((c>>3)&3)*16 + (row&15),
// offset = tile*1024 + half*512 + l*8 + (c&7).  A wave's frag load
// ([row=m16][c=quad*8+j]) is then 64 lanes x 16 B contiguous at tile_base.
__device__ __forceinline__ size_t qk_swz(int row, int c) {
    return (size_t)(row >> 4) * 1024 + (c >> 5) * 512 +
           ((((c >> 3) & 3) * 16 + (row & 15)) * 8) + (c & 7);
}

// ---------- prep: Q,K fp32 -> bf16, frag-major swizzled ----------
__global__ __launch_bounds__(256) void cvt_qk(const float* __restrict__ Q,
                                              const float* __restrict__ K,
                                              unsigned short* __restrict__ Qs,
                                              unsigned short* __restrict__ Ks) {
    int i = (blockIdx.x * 256 + threadIdx.x) * 4;
    int rg = i >> 6, c = i & 63;
    int n = rg >> 12, r = rg & 4095;
    float4 q = *(const float4*)(Q + i);
    float4 k = *(const float4*)(K + i);
    ushort4 qo, ko;
    qo.x = f2bf(q.x); qo.y = f2bf(q.y); qo.z = f2bf(q.z); qo.w = f2bf(q.w);
    ko.x = f2bf(k.x); ko.y = f2bf(k.y); ko.z = f2bf(k.z); ko.w = f2bf(k.w);
    size_t off = (size_t)n * NSTRIDE + qk_swz(r, c);  // c%4==0 -> 8B aligned
    *(ushort4*)(Qs + off) = qo;
    *(ushort4*)(Ks + off) = ko;
}

// ---------- phase 1: l[n,k] = sum_q exp2(C1 * dot(Q[q],K[k])) ----------
// grid (32 k-blocks of 128, NB, 8 q-slices of 512); wave holds 32 stationary k.
__global__ __launch_bounds__(256, 4) void lsum_kernel(const unsigned short* __restrict__ Qs,
                                                      const unsigned short* __restrict__ Ks,
                                                      float* __restrict__ l) {
    int tid = threadIdx.x;
    int w = tid >> 6, lane = tid & 63, quad = lane >> 4, m16 = lane & 15;
    int n = blockIdx.y;
    int kbase = blockIdx.x * 128 + w * 32;

    const unsigned short* Kp = Ks + (size_t)n * NSTRIDE + (kbase >> 4) * 1024 + lane * 8;
    short8 ka0 = *(const short8*)(Kp);
    short8 ka1 = *(const short8*)(Kp + 512);
    short8 kb0 = *(const short8*)(Kp + 1024);
    short8 kb1 = *(const short8*)(Kp + 1536);

    const unsigned short* Qp = Qs + (size_t)n * NSTRIDE + blockIdx.z * 32768 + lane * 8;

    float lA[4] = {0.f, 0.f, 0.f, 0.f};
    float lB[4] = {0.f, 0.f, 0.f, 0.f};
    for (int qc = 0; qc < 32; ++qc) {
        short8 qf0 = *(const short8*)(Qp);
        short8 qf1 = *(const short8*)(Qp + 512);
        f32x4 a = {0.f, 0.f, 0.f, 0.f}, b = {0.f, 0.f, 0.f, 0.f};
        a = __builtin_amdgcn_mfma_f32_16x16x32_bf16(ka0, qf0, a, 0, 0, 0);
        a = __builtin_amdgcn_mfma_f32_16x16x32_bf16(ka1, qf1, a, 0, 0, 0);
        b = __builtin_amdgcn_mfma_f32_16x16x32_bf16(kb0, qf0, b, 0, 0, 0);
        b = __builtin_amdgcn_mfma_f32_16x16x32_bf16(kb1, qf1, b, 0, 0, 0);
#pragma unroll
        for (int r = 0; r < 4; ++r) {
            lA[r] += fexp2(a[r] * C1);
            lB[r] += fexp2(b[r] * C1);
        }
        Qp += 1024;
    }
#pragma unroll
    for (int r = 0; r < 4; ++r)
        for (int d = 1; d < 16; d <<= 1) {
            lA[r] += __shfl_xor(lA[r], d);
            lB[r] += __shfl_xor(lB[r], d);
        }
    if (m16 == 0) {
        float* lp = l + n * HWN + kbase + quad * 4;
#pragma unroll
        for (int r = 0; r < 4; ++r) {
            atomicAdd(lp + r, lA[r]);
            atomicAdd(lp + 16 + r, lB[r]);
        }
    }
}

// ---------- prep: Vts = frag-major bf16(V[n][k][c] / l[n][k]), [c][k]-tiled ----------
// Vt elem(c, k) -> kblock = k>>5, tile ct = c>>4, lane l = ((k>>3)&3)*16 + (c&15),
// offset = kblock*2048 + ct*512 + l*8 + (k&7)
__global__ __launch_bounds__(256) void prep_v(const float* __restrict__ V,
                                              const float* __restrict__ l,
                                              unsigned short* __restrict__ Vts) {
    __shared__ float rl[64];
    __shared__ float tile[64][65];
    int tid = threadIdx.x, n = blockIdx.y, kbase = blockIdx.x * 64;
    if (tid < 64) rl[tid] = 1.0f / l[n * HWN + kbase + tid];
    __syncthreads();
#pragma unroll
    for (int i = 0; i < 16; ++i) {
        int e = i * 256 + tid;
        int k = e >> 6, c = e & 63;
        tile[c][k] = V[((size_t)(n * HWN + kbase + k)) * CD + c] * rl[k];
    }
    __syncthreads();
    // 512 ushort8 stores: s -> c = s>>3, k-group kg = s&7 (8 consecutive k)
#pragma unroll
    for (int i = 0; i < 2; ++i) {
        int s = i * 256 + tid;
        int c = s >> 3, kg = s & 7;
        int kl = kg * 8;          // local k of first elem
        int kgl = kbase + kl;     // global k
        short8 v;
#pragma unroll
        for (int j = 0; j < 8; ++j) v[j] = (short)f2bf(tile[c][kl + j]);
        size_t off = (size_t)n * NSTRIDE + (size_t)(kgl >> 5) * 2048 + (c >> 4) * 512 +
                     ((((kgl >> 3) & 3) * 16 + (c & 15)) * 8);
        *(short8*)(Vts + off) = v;
    }
}

// ---------- phase 2: out[q,c] = sum_k exp2(C1*s_qk) * V[k][c]/l[k] ----------
// grid (64 q-blocks of 64, NB, 2 k-slices). 4 waves share the same 2048-k
// slice (identical coalesced addresses -> L1 dedup); wave w owns q-tile w*16.
__global__ __launch_bounds__(256, 4) void attn_kernel(const unsigned short* __restrict__ Qs,
                                                      const unsigned short* __restrict__ Ks,
                                                      const unsigned short* __restrict__ Vts,
                                                      float* __restrict__ partial) {
    __shared__ short plds[4][16][40];  // per-wave P buffer, stride 40 bf16
    int tid = threadIdx.x;
    int w = tid >> 6, lane = tid & 63, quad = lane >> 4, m16 = lane & 15;
    int n = blockIdx.y;
    int qbase = blockIdx.x * 64 + w * 16;

    const unsigned short* Qp = Qs + (size_t)n * NSTRIDE + (qbase >> 4) * 1024 + lane * 8;
    short8 qf0 = *(const short8*)(Qp);
    short8 qf1 = *(const short8*)(Qp + 512);

    // kslice = z*2048: K tile offset (kslice>>4)*1024 = z*131072; V: (kslice>>5)*2048 = same
    size_t kofs = (size_t)blockIdx.z * 131072;
    const unsigned short* Kp = Ks + (size_t)n * NSTRIDE + kofs + lane * 8;
    const unsigned short* Vp = Vts + (size_t)n * NSTRIDE + kofs + lane * 8;

    f32x4 o[4];
#pragma unroll
    for (int ct = 0; ct < 4; ++ct) o[ct] = f32x4{0.f, 0.f, 0.f, 0.f};

    short* pw = &plds[w][0][0];

    for (int it = 0; it < 64; ++it) {
        // S tile: 16q x 32k. Frag loads: linear 1KB wave-loads, 4KB/iter stream
        short8 kf00 = *(const short8*)(Kp);
        short8 kf01 = *(const short8*)(Kp + 512);
        short8 kf10 = *(const short8*)(Kp + 1024);
        short8 kf11 = *(const short8*)(Kp + 1536);
        f32x4 s0 = {0.f, 0.f, 0.f, 0.f}, s1 = {0.f, 0.f, 0.f, 0.f};
        s0 = __builtin_amdgcn_mfma_f32_16x16x32_bf16(qf0, kf00, s0, 0, 0, 0);
        s0 = __builtin_amdgcn_mfma_f32_16x16x32_bf16(qf1, kf01, s0, 0, 0, 0);
        s1 = __builtin_amdgcn_mfma_f32_16x16x32_bf16(qf0, kf10, s1, 0, 0, 0);
        s1 = __builtin_amdgcn_mfma_f32_16x16x32_bf16(qf1, kf11, s1, 0, 0, 0);

        // P = exp2(C1*s) -> per-wave LDS (rows=q, stride 40); in-wave DS in-order
        short* prow = pw + (quad * 4) * 40 + m16;
#pragma unroll
        for (int r = 0; r < 4; ++r) {
            prow[r * 40]      = (short)f2bf(fexp2(s0[r] * C1));
            prow[r * 40 + 16] = (short)f2bf(fexp2(s1[r] * C1));
        }
        // A-frag read: A[m=q=m16][k=quad*8+j]
        short8 pf = *(const short8*)(pw + m16 * 40 + quad * 8);

#pragma unroll
        for (int ct = 0; ct < 4; ++ct) {
            short8 vf = *(const short8*)(Vp + ct * 512);
            o[ct] = __builtin_amdgcn_mfma_f32_16x16x32_bf16(pf, vf, o[ct], 0, 0, 0);
        }
        Kp += 2048;
        Vp += 2048;
        if ((it & 7) == 7) __syncthreads();  // lockstep for L1 reuse across waves
    }

    // o[ct][r] = O_partial[q = quad*4+r][c = ct*16 + m16]; plain stores
    float* pp = partial + (size_t)blockIdx.z * (NB * HWN * CD) +
                ((size_t)(n * HWN + qbase + quad * 4)) * CD + m16;
#pragma unroll
    for (int ct = 0; ct < 4; ++ct)
#pragma unroll
        for (int r = 0; r < 4; ++r)
            pp[r * CD + ct * 16] = o[ct][r];
}

// ---------- final: out = partial[0] + partial[1] ----------
__global__ __launch_bounds__(256) void reduce_out(const float* __restrict__ p,
                                                  float* __restrict__ out) {
    int i = (blockIdx.x * 256 + threadIdx.x) * 4;
    f32x4 a = *(const f32x4*)(p + i);
    f32x4 b = *(const f32x4*)(p + (NB * HWN * CD) + i);
    a = a + b;
    *(f32x4*)(out + i) = a;
}

extern "C" void kernel_launch(void* const* d_in, const int* in_sizes, int n_in,
                              void* d_out, int out_size, void* d_ws, size_t ws_size,
                              hipStream_t stream) {
    const float* Q = (const float*)d_in[0];
    const float* K = (const float*)d_in[1];
    const float* V = (const float*)d_in[2];
    float* out = (float*)d_out;

    char* ws = (char*)d_ws;
    unsigned short* Qs  = (unsigned short*)(ws);                   // 2 MB
    unsigned short* Ks  = (unsigned short*)(ws + (1u << 21));      // 2 MB
    unsigned short* Vts = (unsigned short*)(ws + (2u << 21));      // 2 MB
    float* l       = (float*)(ws + (3u << 21));                    // 64 KB
    float* partial = (float*)(ws + (4u << 21));                    // 8 MB (2 slices)

    hipMemsetAsync(l, 0, (size_t)NB * HWN * sizeof(float), stream);

    cvt_qk<<<1024, 256, 0, stream>>>(Q, K, Qs, Ks);
    lsum_kernel<<<dim3(32, NB, 8), 256, 0, stream>>>(Qs, Ks, l);
    prep_v<<<dim3(64, NB), 256, 0, stream>>>(V, l, Vts);
    attn_kernel<<<dim3(64, NB, 2), 256, 0, stream>>>(Qs, Ks, Vts, partial);
    reduce_out<<<1024, 256, 0, stream>>>(partial, out);
}

// Round 6
// 133.000 us; speedup vs baseline: 2.2881x; 1.0519x over previous
//
#include <hip/hip_runtime.h>

#define NB 4
#define HWN 4096
#define CD 64
#define NSTRIDE (HWN * CD)  // 262144 elems per batch in all swizzled buffers

typedef short short8 __attribute__((ext_vector_type(8), may_alias));
typedef float f32x4 __attribute__((ext_vector_type(4), may_alias));

__device__ constexpr float C1 = 0.18033688011112042f; // log2(e)/8

__device__ __forceinline__ unsigned short f2bf(float f) {
    unsigned u = __builtin_bit_cast(unsigned, f);
    u = (u + 0x7FFFu + ((u >> 16) & 1u)) >> 16;  // RTN-even
    return (unsigned short)u;
}

__device__ __forceinline__ float fexp2(float x) {
#if __has_builtin(__builtin_amdgcn_exp2f)
    return __builtin_amdgcn_exp2f(x);
#else
    return exp2f(x);
#endif
}

// Frag-major swizzle for a row-major [R][64] matrix, 16-row tiles:
// elem(row, c) -> tile = row>>4, half = c>>5, lane l = ((c>>3)&3)*16 + (row&15),
// offset = tile*1024 + half*512 + l*8 + (c&7).  A wave's frag load
// ([row=m16][c=quad*8+j]) is then 64 lanes x 16 B contiguous at tile_base.
__device__ __forceinline__ size_t qk_swz(int row, int c) {
    return (size_t)(row >> 4) * 1024 + (c >> 5) * 512 +
           ((((c >> 3) & 3) * 16 + (row & 15)) * 8) + (c & 7);
}

// ---------- prep: Q,K fp32 -> bf16, frag-major swizzled ----------
__global__ __launch_bounds__(256) void cvt_qk(const float* __restrict__ Q,
                                              const float* __restrict__ K,
                                              unsigned short* __restrict__ Qs,
                                              unsigned short* __restrict__ Ks) {
    int i = (blockIdx.x * 256 + threadIdx.x) * 4;
    int rg = i >> 6, c = i & 63;
    int n = rg >> 12, r = rg & 4095;
    float4 q = *(const float4*)(Q + i);
    float4 k = *(const float4*)(K + i);
    ushort4 qo, ko;
    qo.x = f2bf(q.x); qo.y = f2bf(q.y); qo.z = f2bf(q.z); qo.w = f2bf(q.w);
    ko.x = f2bf(k.x); ko.y = f2bf(k.y); ko.z = f2bf(k.z); ko.w = f2bf(k.w);
    size_t off = (size_t)n * NSTRIDE + qk_swz(r, c);  // c%4==0 -> 8B aligned
    *(ushort4*)(Qs + off) = qo;
    *(ushort4*)(Ks + off) = ko;
}

// ---------- phase 1: l[n,k] = sum_q exp2(C1 * dot(Q[q],K[k])) ----------
// grid (32 k-blocks of 128, NB, 8 q-slices of 512); wave holds 32 stationary k.
__global__ __launch_bounds__(256, 4) void lsum_kernel(const unsigned short* __restrict__ Qs,
                                                      const unsigned short* __restrict__ Ks,
                                                      float* __restrict__ l) {
    int tid = threadIdx.x;
    int w = tid >> 6, lane = tid & 63, quad = lane >> 4, m16 = lane & 15;
    int n = blockIdx.y;
    int kbase = blockIdx.x * 128 + w * 32;

    const unsigned short* Kp = Ks + (size_t)n * NSTRIDE + (kbase >> 4) * 1024 + lane * 8;
    short8 ka0 = *(const short8*)(Kp);
    short8 ka1 = *(const short8*)(Kp + 512);
    short8 kb0 = *(const short8*)(Kp + 1024);
    short8 kb1 = *(const short8*)(Kp + 1536);

    const unsigned short* Qp = Qs + (size_t)n * NSTRIDE + blockIdx.z * 32768 + lane * 8;

    float lA[4] = {0.f, 0.f, 0.f, 0.f};
    float lB[4] = {0.f, 0.f, 0.f, 0.f};
#pragma unroll 4
    for (int qc = 0; qc < 32; ++qc) {
        short8 qf0 = *(const short8*)(Qp);
        short8 qf1 = *(const short8*)(Qp + 512);
        f32x4 a = {0.f, 0.f, 0.f, 0.f}, b = {0.f, 0.f, 0.f, 0.f};
        a = __builtin_amdgcn_mfma_f32_16x16x32_bf16(ka0, qf0, a, 0, 0, 0);
        a = __builtin_amdgcn_mfma_f32_16x16x32_bf16(ka1, qf1, a, 0, 0, 0);
        b = __builtin_amdgcn_mfma_f32_16x16x32_bf16(kb0, qf0, b, 0, 0, 0);
        b = __builtin_amdgcn_mfma_f32_16x16x32_bf16(kb1, qf1, b, 0, 0, 0);
#pragma unroll
        for (int r = 0; r < 4; ++r) {
            lA[r] += fexp2(a[r] * C1);
            lB[r] += fexp2(b[r] * C1);
        }
        Qp += 1024;
    }
#pragma unroll
    for (int r = 0; r < 4; ++r)
        for (int d = 1; d < 16; d <<= 1) {
            lA[r] += __shfl_xor(lA[r], d);
            lB[r] += __shfl_xor(lB[r], d);
        }
    if (m16 == 0) {
        float* lp = l + n * HWN + kbase + quad * 4;
#pragma unroll
        for (int r = 0; r < 4; ++r) {
            atomicAdd(lp + r, lA[r]);
            atomicAdd(lp + 16 + r, lB[r]);
        }
    }
}

// ---------- prep: Vts = frag-major bf16(V[n][k][c] / l[n][k]), [c][k]-tiled ----------
__global__ __launch_bounds__(256) void prep_v(const float* __restrict__ V,
                                              const float* __restrict__ l,
                                              unsigned short* __restrict__ Vts) {
    __shared__ float rl[64];
    __shared__ float tile[64][65];
    int tid = threadIdx.x, n = blockIdx.y, kbase = blockIdx.x * 64;
    if (tid < 64) rl[tid] = 1.0f / l[n * HWN + kbase + tid];
    __syncthreads();
#pragma unroll
    for (int i = 0; i < 16; ++i) {
        int e = i * 256 + tid;
        int k = e >> 6, c = e & 63;
        tile[c][k] = V[((size_t)(n * HWN + kbase + k)) * CD + c] * rl[k];
    }
    __syncthreads();
#pragma unroll
    for (int i = 0; i < 2; ++i) {
        int s = i * 256 + tid;
        int c = s >> 3, kg = s & 7;
        int kl = kg * 8;
        int kgl = kbase + kl;
        short8 v;
#pragma unroll
        for (int j = 0; j < 8; ++j) v[j] = (short)f2bf(tile[c][kl + j]);
        size_t off = (size_t)n * NSTRIDE + (size_t)(kgl >> 5) * 2048 + (c >> 4) * 512 +
                     ((((kgl >> 3) & 3) * 16 + (c & 15)) * 8);
        *(short8*)(Vts + off) = v;
    }
}

// ---------- phase 2: out[q,c] = sum_k exp2(C1*s_qk) * V[k][c]/l[k] ----------
// grid (64 q-blocks of 64, NB, ns k-slices). 4 waves share the same k-slice
// (identical coalesced addresses -> L1 dedup); wave w owns q-tile w*16.
// Loop = nseg straight-line 8-iter segments with a lockstep barrier between.
__global__ __launch_bounds__(256, 4) void attn_kernel(const unsigned short* __restrict__ Qs,
                                                      const unsigned short* __restrict__ Ks,
                                                      const unsigned short* __restrict__ Vts,
                                                      float* __restrict__ partial,
                                                      int nseg) {
    __shared__ short plds[4][16][40];  // per-wave P buffer, stride 40 bf16
    int tid = threadIdx.x;
    int w = tid >> 6, lane = tid & 63, quad = lane >> 4, m16 = lane & 15;
    int n = blockIdx.y;
    int qbase = blockIdx.x * 64 + w * 16;

    const unsigned short* Qp = Qs + (size_t)n * NSTRIDE + (qbase >> 4) * 1024 + lane * 8;
    short8 qf0 = *(const short8*)(Qp);
    short8 qf1 = *(const short8*)(Qp + 512);

    // k-slice byte layout: each 32-k chunk is 2048 elems in both Ks and Vts
    size_t kofs = (size_t)blockIdx.z * (size_t)nseg * 8 * 2048;
    const unsigned short* Kp = Ks + (size_t)n * NSTRIDE + kofs + lane * 8;
    const unsigned short* Vp = Vts + (size_t)n * NSTRIDE + kofs + lane * 8;

    f32x4 o[4];
#pragma unroll
    for (int ct = 0; ct < 4; ++ct) o[ct] = f32x4{0.f, 0.f, 0.f, 0.f};

    short* pw = &plds[w][0][0];

    for (int seg = 0; seg < nseg; ++seg) {
#pragma unroll
        for (int it = 0; it < 8; ++it) {
            // S tile: 16q x 32k. Frag loads: linear 1KB wave-loads, 4KB/iter stream
            short8 kf00 = *(const short8*)(Kp);
            short8 kf01 = *(const short8*)(Kp + 512);
            short8 kf10 = *(const short8*)(Kp + 1024);
            short8 kf11 = *(const short8*)(Kp + 1536);
            f32x4 s0 = {0.f, 0.f, 0.f, 0.f}, s1 = {0.f, 0.f, 0.f, 0.f};
            s0 = __builtin_amdgcn_mfma_f32_16x16x32_bf16(qf0, kf00, s0, 0, 0, 0);
            s0 = __builtin_amdgcn_mfma_f32_16x16x32_bf16(qf1, kf01, s0, 0, 0, 0);
            s1 = __builtin_amdgcn_mfma_f32_16x16x32_bf16(qf0, kf10, s1, 0, 0, 0);
            s1 = __builtin_amdgcn_mfma_f32_16x16x32_bf16(qf1, kf11, s1, 0, 0, 0);

            // P = exp2(C1*s) -> per-wave LDS (rows=q, stride 40); in-wave DS in-order
            short* prow = pw + (quad * 4) * 40 + m16;
#pragma unroll
            for (int r = 0; r < 4; ++r) {
                prow[r * 40]      = (short)f2bf(fexp2(s0[r] * C1));
                prow[r * 40 + 16] = (short)f2bf(fexp2(s1[r] * C1));
            }
            // A-frag read: A[m=q=m16][k=quad*8+j]
            short8 pf = *(const short8*)(pw + m16 * 40 + quad * 8);

#pragma unroll
            for (int ct = 0; ct < 4; ++ct) {
                short8 vf = *(const short8*)(Vp + ct * 512);
                o[ct] = __builtin_amdgcn_mfma_f32_16x16x32_bf16(pf, vf, o[ct], 0, 0, 0);
            }
            Kp += 2048;
            Vp += 2048;
        }
        __syncthreads();  // lockstep the block's 4 waves for L1 reuse
    }

    // o[ct][r] = O_partial[q = quad*4+r][c = ct*16 + m16]; plain stores
    float* pp = partial + (size_t)blockIdx.z * (NB * HWN * CD) +
                ((size_t)(n * HWN + qbase + quad * 4)) * CD + m16;
#pragma unroll
    for (int ct = 0; ct < 4; ++ct)
#pragma unroll
        for (int r = 0; r < 4; ++r)
            pp[r * CD + ct * 16] = o[ct][r];
}

// ---------- final: out = sum of ns partial slices ----------
__global__ __launch_bounds__(256) void reduce_out(const float* __restrict__ p,
                                                  float* __restrict__ out, int ns) {
    int i = (blockIdx.x * 256 + threadIdx.x) * 4;
    f32x4 a = *(const f32x4*)(p + i);
    for (int s = 1; s < ns; ++s)
        a = a + *(const f32x4*)(p + (size_t)s * (NB * HWN * CD) + i);
    *(f32x4*)(out + i) = a;
}

extern "C" void kernel_launch(void* const* d_in, const int* in_sizes, int n_in,
                              void* d_out, int out_size, void* d_ws, size_t ws_size,
                              hipStream_t stream) {
    const float* Q = (const float*)d_in[0];
    const float* K = (const float*)d_in[1];
    const float* V = (const float*)d_in[2];
    float* out = (float*)d_out;

    char* ws = (char*)d_ws;
    unsigned short* Qs  = (unsigned short*)(ws);                   // 2 MB
    unsigned short* Ks  = (unsigned short*)(ws + (1u << 21));      // 2 MB
    unsigned short* Vts = (unsigned short*)(ws + (2u << 21));      // 2 MB
    float* l       = (float*)(ws + (3u << 21));                    // 64 KB
    float* partial = (float*)(ws + (4u << 21));                    // ns * 4 MB

    // ns k-slices: prefer 4 (16 waves/CU) if scratch allows, else 2
    size_t base = (size_t)(4u << 21);
    size_t slice = (size_t)NB * HWN * CD * sizeof(float);
    int ns = (ws_size >= base + 4 * slice) ? 4 : 2;
    int nseg = (HWN / ns) / 32 / 8;  // 8-iter segments per wave: ns=4 -> 4, ns=2 -> 8

    hipMemsetAsync(l, 0, (size_t)NB * HWN * sizeof(float), stream);

    cvt_qk<<<1024, 256, 0, stream>>>(Q, K, Qs, Ks);
    lsum_kernel<<<dim3(32, NB, 8), 256, 0, stream>>>(Qs, Ks, l);
    prep_v<<<dim3(64, NB), 256, 0, stream>>>(V, l, Vts);
    attn_kernel<<<dim3(64, NB, ns), 256, 0, stream>>>(Qs, Ks, Vts, partial, nseg);
    reduce_out<<<1024, 256, 0, stream>>>(partial, out, ns);
}

// Round 7
// 124.294 us; speedup vs baseline: 2.4484x; 1.0700x over previous
//
#include <hip/hip_runtime.h>

#define NB 4
#define HWN 4096
#define CD 64
#define NSTRIDE (HWN * CD)  // 262144 elems per batch in all swizzled buffers

typedef short short8 __attribute__((ext_vector_type(8), may_alias));
typedef float f32x4 __attribute__((ext_vector_type(4), may_alias));

__device__ constexpr float C1 = 0.18033688011112042f; // log2(e)/8

__device__ __forceinline__ unsigned short f2bf(float f) {
    unsigned u = __builtin_bit_cast(unsigned, f);
    u = (u + 0x7FFFu + ((u >> 16) & 1u)) >> 16;  // RTN-even
    return (unsigned short)u;
}

__device__ __forceinline__ float fexp2(float x) {
#if __has_builtin(__builtin_amdgcn_exp2f)
    return __builtin_amdgcn_exp2f(x);
#else
    return exp2f(x);
#endif
}

// Frag-major swizzle for a row-major [R][64] matrix, 16-row tiles:
// elem(row, c) -> tile = row>>4, half = c>>5, lane l = ((c>>3)&3)*16 + (row&15),
// offset = tile*1024 + half*512 + l*8 + (c&7).
__device__ __forceinline__ size_t qk_swz(int row, int c) {
    return (size_t)(row >> 4) * 1024 + (c >> 5) * 512 +
           ((((c >> 3) & 3) * 16 + (row & 15)) * 8) + (c & 7);
}

// ---------- prep: Q,K fp32 -> bf16, frag-major swizzled ----------
__global__ __launch_bounds__(256) void cvt_qk(const float* __restrict__ Q,
                                              const float* __restrict__ K,
                                              unsigned short* __restrict__ Qs,
                                              unsigned short* __restrict__ Ks) {
    int i = (blockIdx.x * 256 + threadIdx.x) * 4;
    int rg = i >> 6, c = i & 63;
    int n = rg >> 12, r = rg & 4095;
    float4 q = *(const float4*)(Q + i);
    float4 k = *(const float4*)(K + i);
    ushort4 qo, ko;
    qo.x = f2bf(q.x); qo.y = f2bf(q.y); qo.z = f2bf(q.z); qo.w = f2bf(q.w);
    ko.x = f2bf(k.x); ko.y = f2bf(k.y); ko.z = f2bf(k.z); ko.w = f2bf(k.w);
    size_t off = (size_t)n * NSTRIDE + qk_swz(r, c);
    *(ushort4*)(Qs + off) = qo;
    *(ushort4*)(Ks + off) = ko;
}

// ---------- phase 1: l[n,k] = sum_q exp2(C1 * dot(Q[q],K[k])) ----------
// grid (32 k-blocks of 128, NB, 16 q-slices of 256); wave holds 32 stationary k.
// Q stream register-prefetched one iteration ahead; no barriers, no LDS.
__global__ __launch_bounds__(256, 8) void lsum_kernel(const unsigned short* __restrict__ Qs,
                                                      const unsigned short* __restrict__ Ks,
                                                      float* __restrict__ l) {
    int tid = threadIdx.x;
    int w = tid >> 6, lane = tid & 63, quad = lane >> 4, m16 = lane & 15;
    int n = blockIdx.y;
    int kbase = blockIdx.x * 128 + w * 32;

    const unsigned short* Kp = Ks + (size_t)n * NSTRIDE + (kbase >> 4) * 1024 + lane * 8;
    short8 ka0 = *(const short8*)(Kp);
    short8 ka1 = *(const short8*)(Kp + 512);
    short8 kb0 = *(const short8*)(Kp + 1024);
    short8 kb1 = *(const short8*)(Kp + 1536);

    const unsigned short* Qp = Qs + (size_t)n * NSTRIDE + blockIdx.z * 16384 + lane * 8;

    short8 qc0 = *(const short8*)(Qp);
    short8 qc1 = *(const short8*)(Qp + 512);
    Qp += 1024;

    float lA[4] = {0.f, 0.f, 0.f, 0.f};
    float lB[4] = {0.f, 0.f, 0.f, 0.f};
#pragma unroll 2
    for (int qc = 0; qc < 16; ++qc) {
        short8 qn0 = *(const short8*)(Qp);        // prefetch next (overread at end: in-ws)
        short8 qn1 = *(const short8*)(Qp + 512);
        f32x4 a = {0.f, 0.f, 0.f, 0.f}, b = {0.f, 0.f, 0.f, 0.f};
        a = __builtin_amdgcn_mfma_f32_16x16x32_bf16(ka0, qc0, a, 0, 0, 0);
        a = __builtin_amdgcn_mfma_f32_16x16x32_bf16(ka1, qc1, a, 0, 0, 0);
        b = __builtin_amdgcn_mfma_f32_16x16x32_bf16(kb0, qc0, b, 0, 0, 0);
        b = __builtin_amdgcn_mfma_f32_16x16x32_bf16(kb1, qc1, b, 0, 0, 0);
#pragma unroll
        for (int r = 0; r < 4; ++r) {
            lA[r] += fexp2(a[r] * C1);
            lB[r] += fexp2(b[r] * C1);
        }
        qc0 = qn0; qc1 = qn1;
        Qp += 1024;
    }
#pragma unroll
    for (int r = 0; r < 4; ++r)
        for (int d = 1; d < 16; d <<= 1) {
            lA[r] += __shfl_xor(lA[r], d);
            lB[r] += __shfl_xor(lB[r], d);
        }
    if (m16 == 0) {
        float* lp = l + n * HWN + kbase + quad * 4;
#pragma unroll
        for (int r = 0; r < 4; ++r) {
            atomicAdd(lp + r, lA[r]);
            atomicAdd(lp + 16 + r, lB[r]);
        }
    }
}

// ---------- prep: Vts = frag-major bf16(V[n][k][c] / l[n][k]), [c][k]-tiled ----------
__global__ __launch_bounds__(256) void prep_v(const float* __restrict__ V,
                                              const float* __restrict__ l,
                                              unsigned short* __restrict__ Vts) {
    __shared__ float rl[64];
    __shared__ float tile[64][65];
    int tid = threadIdx.x, n = blockIdx.y, kbase = blockIdx.x * 64;
    if (tid < 64) rl[tid] = 1.0f / l[n * HWN + kbase + tid];
    __syncthreads();
#pragma unroll
    for (int i = 0; i < 16; ++i) {
        int e = i * 256 + tid;
        int k = e >> 6, c = e & 63;
        tile[c][k] = V[((size_t)(n * HWN + kbase + k)) * CD + c] * rl[k];
    }
    __syncthreads();
#pragma unroll
    for (int i = 0; i < 2; ++i) {
        int s = i * 256 + tid;
        int c = s >> 3, kg = s & 7;
        int kl = kg * 8;
        int kgl = kbase + kl;
        short8 v;
#pragma unroll
        for (int j = 0; j < 8; ++j) v[j] = (short)f2bf(tile[c][kl + j]);
        size_t off = (size_t)n * NSTRIDE + (size_t)(kgl >> 5) * 2048 + (c >> 4) * 512 +
                     ((((kgl >> 3) & 3) * 16 + (c & 15)) * 8);
        *(short8*)(Vts + off) = v;
    }
}

// ---------- phase 2: out[q,c] = sum_k exp2(C1*s_qk) * V[k][c]/l[k] ----------
// grid (64 q-blocks of 64, NB, ns k-slices). Wave w owns q-tile w*16.
// Software pipeline: K/V register-prefetched 1 iter ahead; P goes through a
// per-wave double-buffered LDS transpose consumed one iteration later.
__global__ __launch_bounds__(256, 4) void attn_kernel(const unsigned short* __restrict__ Qs,
                                                      const unsigned short* __restrict__ Ks,
                                                      const unsigned short* __restrict__ Vts,
                                                      float* __restrict__ partial,
                                                      int nit) {
    __shared__ short plds[4][2][16][40];  // [wave][buf][q-row][k], stride 40 bf16
    int tid = threadIdx.x;
    int w = tid >> 6, lane = tid & 63, quad = lane >> 4, m16 = lane & 15;
    int n = blockIdx.y;
    int qbase = blockIdx.x * 64 + w * 16;

    const unsigned short* Qp = Qs + (size_t)n * NSTRIDE + (qbase >> 4) * 1024 + lane * 8;
    short8 qf0 = *(const short8*)(Qp);
    short8 qf1 = *(const short8*)(Qp + 512);

    size_t kofs = (size_t)blockIdx.z * (size_t)nit * 2048;
    const unsigned short* Kp = Ks + (size_t)n * NSTRIDE + kofs + lane * 8;
    const unsigned short* Vp = Vts + (size_t)n * NSTRIDE + kofs + lane * 8;

    f32x4 o[4];
#pragma unroll
    for (int ct = 0; ct < 4; ++ct) o[ct] = f32x4{0.f, 0.f, 0.f, 0.f};

    short* pw0 = &plds[w][0][0][0];
    short* pw1 = &plds[w][1][0][0];
    int wr_off = (quad * 4) * 40 + m16;   // P store base (C-layout row=q, col=k)
    int rd_off = m16 * 40 + quad * 8;     // A-frag read base

    short8 kc0, kc1, kc2, kc3, vp0, vp1, vp2, vp3;

    // ---- prologue: it = 0 ----
    kc0 = *(const short8*)(Kp);
    kc1 = *(const short8*)(Kp + 512);
    kc2 = *(const short8*)(Kp + 1024);
    kc3 = *(const short8*)(Kp + 1536);
    Kp += 2048;
    vp0 = *(const short8*)(Vp);
    vp1 = *(const short8*)(Vp + 512);
    vp2 = *(const short8*)(Vp + 1024);
    vp3 = *(const short8*)(Vp + 1536);
    Vp += 2048;
    {
        f32x4 s0 = {0.f, 0.f, 0.f, 0.f}, s1 = {0.f, 0.f, 0.f, 0.f};
        s0 = __builtin_amdgcn_mfma_f32_16x16x32_bf16(qf0, kc0, s0, 0, 0, 0);
        s0 = __builtin_amdgcn_mfma_f32_16x16x32_bf16(qf1, kc1, s0, 0, 0, 0);
        s1 = __builtin_amdgcn_mfma_f32_16x16x32_bf16(qf0, kc2, s1, 0, 0, 0);
        s1 = __builtin_amdgcn_mfma_f32_16x16x32_bf16(qf1, kc3, s1, 0, 0, 0);
        short* prow = pw0 + wr_off;
#pragma unroll
        for (int r = 0; r < 4; ++r) {
            prow[r * 40]      = (short)f2bf(fexp2(s0[r] * C1));
            prow[r * 40 + 16] = (short)f2bf(fexp2(s1[r] * C1));
        }
    }
    // K(1) for the first loop body
    kc0 = *(const short8*)(Kp);
    kc1 = *(const short8*)(Kp + 512);
    kc2 = *(const short8*)(Kp + 1024);
    kc3 = *(const short8*)(Kp + 1536);
    Kp += 2048;

    // ---- pipelined body: it = 1 .. nit-1 ----
#pragma unroll 2
    for (int it = 1; it < nit; ++it) {
        // prefetch K(it+1) (overread at it=nit-1: lands in-ws, unused)
        short8 kn0 = *(const short8*)(Kp);
        short8 kn1 = *(const short8*)(Kp + 512);
        short8 kn2 = *(const short8*)(Kp + 1024);
        short8 kn3 = *(const short8*)(Kp + 1536);
        Kp += 2048;
        // V(it): consumed next iteration
        short8 vn0 = *(const short8*)(Vp);
        short8 vn1 = *(const short8*)(Vp + 512);
        short8 vn2 = *(const short8*)(Vp + 1024);
        short8 vn3 = *(const short8*)(Vp + 1536);
        Vp += 2048;

        // S(it) from kc = K(it), loaded one iteration ago
        f32x4 s0 = {0.f, 0.f, 0.f, 0.f}, s1 = {0.f, 0.f, 0.f, 0.f};
        s0 = __builtin_amdgcn_mfma_f32_16x16x32_bf16(qf0, kc0, s0, 0, 0, 0);
        s0 = __builtin_amdgcn_mfma_f32_16x16x32_bf16(qf1, kc1, s0, 0, 0, 0);
        s1 = __builtin_amdgcn_mfma_f32_16x16x32_bf16(qf0, kc2, s1, 0, 0, 0);
        s1 = __builtin_amdgcn_mfma_f32_16x16x32_bf16(qf1, kc3, s1, 0, 0, 0);

        // P(it-1): written one iteration ago -> DS latency already paid
        short* pr = ((it & 1) ? pw0 : pw1) + rd_off;
        short8 pf = *(const short8*)pr;
#pragma unroll
        for (int ct = 0; ct < 4; ++ct) {
            short8 vf;
            switch (ct) { case 0: vf = vp0; break; case 1: vf = vp1; break;
                          case 2: vf = vp2; break; default: vf = vp3; }
            o[ct] = __builtin_amdgcn_mfma_f32_16x16x32_bf16(pf, vf, o[ct], 0, 0, 0);
        }

        // P(it) -> other LDS buffer
        short* prow = ((it & 1) ? pw1 : pw0) + wr_off;
#pragma unroll
        for (int r = 0; r < 4; ++r) {
            prow[r * 40]      = (short)f2bf(fexp2(s0[r] * C1));
            prow[r * 40 + 16] = (short)f2bf(fexp2(s1[r] * C1));
        }

        kc0 = kn0; kc1 = kn1; kc2 = kn2; kc3 = kn3;
        vp0 = vn0; vp1 = vn1; vp2 = vn2; vp3 = vn3;
    }

    // ---- epilogue: PV for it = nit-1 ----
    {
        short* pr = ((nit & 1) ? pw0 : pw1) + rd_off;
        short8 pf = *(const short8*)pr;
        o[0] = __builtin_amdgcn_mfma_f32_16x16x32_bf16(pf, vp0, o[0], 0, 0, 0);
        o[1] = __builtin_amdgcn_mfma_f32_16x16x32_bf16(pf, vp1, o[1], 0, 0, 0);
        o[2] = __builtin_amdgcn_mfma_f32_16x16x32_bf16(pf, vp2, o[2], 0, 0, 0);
        o[3] = __builtin_amdgcn_mfma_f32_16x16x32_bf16(pf, vp3, o[3], 0, 0, 0);
    }

    // o[ct][r] = O_partial[q = quad*4+r][c = ct*16 + m16]; plain stores
    float* pp = partial + (size_t)blockIdx.z * (NB * HWN * CD) +
                ((size_t)(n * HWN + qbase + quad * 4)) * CD + m16;
#pragma unroll
    for (int ct = 0; ct < 4; ++ct)
#pragma unroll
        for (int r = 0; r < 4; ++r)
            pp[r * CD + ct * 16] = o[ct][r];
}

// ---------- final: out = sum of ns partial slices ----------
__global__ __launch_bounds__(256) void reduce_out(const float* __restrict__ p,
                                                  float* __restrict__ out, int ns) {
    int i = (blockIdx.x * 256 + threadIdx.x) * 4;
    f32x4 a = *(const f32x4*)(p + i);
    for (int s = 1; s < ns; ++s)
        a = a + *(const f32x4*)(p + (size_t)s * (NB * HWN * CD) + i);
    *(f32x4*)(out + i) = a;
}

extern "C" void kernel_launch(void* const* d_in, const int* in_sizes, int n_in,
                              void* d_out, int out_size, void* d_ws, size_t ws_size,
                              hipStream_t stream) {
    const float* Q = (const float*)d_in[0];
    const float* K = (const float*)d_in[1];
    const float* V = (const float*)d_in[2];
    float* out = (float*)d_out;

    char* ws = (char*)d_ws;
    unsigned short* Qs  = (unsigned short*)(ws);                   // 2 MB
    unsigned short* Ks  = (unsigned short*)(ws + (1u << 21));      // 2 MB
    unsigned short* Vts = (unsigned short*)(ws + (2u << 21));      // 2 MB
    float* l       = (float*)(ws + (3u << 21));                    // 64 KB
    float* partial = (float*)(ws + (4u << 21));                    // ns * 4 MB

    size_t base = (size_t)(4u << 21);
    size_t slice = (size_t)NB * HWN * CD * sizeof(float);
    int ns = (ws_size >= base + 4 * slice) ? 4 : 2;
    int nit = HWN / ns / 32;  // 32-k steps per wave: ns=4 -> 32, ns=2 -> 64

    hipMemsetAsync(l, 0, (size_t)NB * HWN * sizeof(float), stream);

    cvt_qk<<<1024, 256, 0, stream>>>(Q, K, Qs, Ks);
    lsum_kernel<<<dim3(32, NB, 16), 256, 0, stream>>>(Qs, Ks, l);
    prep_v<<<dim3(64, NB), 256, 0, stream>>>(V, l, Vts);
    attn_kernel<<<dim3(64, NB, ns), 256, 0, stream>>>(Qs, Ks, Vts, partial, nit);
    reduce_out<<<1024, 256, 0, stream>>>(partial, out, ns);
}